// Round 6
// baseline (1789.338 us; speedup 1.0000x reference)
//
#include <hip/hip_runtime.h>
#include <hip/hip_bf16.h>
#include <stdint.h>

typedef __bf16 bf16x8 __attribute__((ext_vector_type(8)));
typedef float f32x4 __attribute__((ext_vector_type(4)));
typedef unsigned short u16x8 __attribute__((ext_vector_type(8)));

// float -> bf16 round-to-nearest-even (bit trick; inputs are finite here)
__device__ inline unsigned short f2bf_rne(float f) {
  unsigned int u = __float_as_uint(f);
  u += 0x7fffu + ((u >> 16) & 1u);
  return (unsigned short)(u >> 16);
}

// w = mu + eps * exp(0.5*lv), packed bf16. 8 elems/thread, 16B store.
__global__ __launch_bounds__(256) void prep_weight(
    const float4* __restrict__ mu, const float4* __restrict__ lv,
    const float4* __restrict__ eps, u16x8* __restrict__ wbf, int n8) {
  int i = blockIdx.x * 256 + threadIdx.x;
  if (i >= n8) return;
  float4 m0 = mu[2 * i], m1 = mu[2 * i + 1];
  float4 v0 = lv[2 * i], v1 = lv[2 * i + 1];
  float4 e0 = eps[2 * i], e1 = eps[2 * i + 1];
  u16x8 p;
  p[0] = f2bf_rne(m0.x + e0.x * __expf(0.5f * v0.x));
  p[1] = f2bf_rne(m0.y + e0.y * __expf(0.5f * v0.y));
  p[2] = f2bf_rne(m0.z + e0.z * __expf(0.5f * v0.z));
  p[3] = f2bf_rne(m0.w + e0.w * __expf(0.5f * v0.w));
  p[4] = f2bf_rne(m1.x + e1.x * __expf(0.5f * v1.x));
  p[5] = f2bf_rne(m1.y + e1.y * __expf(0.5f * v1.y));
  p[6] = f2bf_rne(m1.z + e1.z * __expf(0.5f * v1.z));
  p[7] = f2bf_rne(m1.w + e1.w * __expf(0.5f * v1.w));
  wbf[i] = p;
}

__global__ __launch_bounds__(256) void prep_x(
    const float4* __restrict__ x, u16x8* __restrict__ xbf, int n8) {
  int i = blockIdx.x * 256 + threadIdx.x;
  if (i >= n8) return;
  float4 m0 = x[2 * i], m1 = x[2 * i + 1];
  u16x8 p;
  p[0] = f2bf_rne(m0.x); p[1] = f2bf_rne(m0.y);
  p[2] = f2bf_rne(m0.z); p[3] = f2bf_rne(m0.w);
  p[4] = f2bf_rne(m1.x); p[5] = f2bf_rne(m1.y);
  p[6] = f2bf_rne(m1.z); p[7] = f2bf_rne(m1.w);
  xbf[i] = p;
}

// C[M,N] = A[M,K]*B[N,K]^T + bias(N). 256x256 tile, BK=64, 512 thr = 8 waves
// (2M x 4N), per-wave 128x64 output: acc[8][4], 64 MFMA/K-tile in 4 phases.
// R6: register-level phase pipeline. Fragments for phase k+1 are ds_read in
// phase k (drained by lgkmcnt(0) at phase END, before the barrier), so the
// LDS service of phase k+1's reads overlaps phase k's MFMA within each wave
// -- breaking R5's read/MFMA lockstep (38% MfmaUtil = serial LDS+MFMA).
//   P0: MFMA a0 x b01 (acc[0..3][0..1]); read a1(8)
//   P1: MFMA a1 x b01 (acc[4..7][0..1]); read b23(4); stage A(t+2)->buf c
//   P2: MFMA a1 x b23 (acc[4..7][2..3]); stage B(t+2)->buf c; vmcnt(8)
//   P3: MFMA a0 x b23 (acc[0..3][2..3]); pre-read a0',b01'(12) from buf n
// WAR: A[c] reads end at P0 (drained before P0-end barrier) -> stage A at P1;
// B[c] reads end at P1 -> stage B at P2. Buf-n pre-read at P3 is certified by
// P2's vmcnt(8)+barrier (each wave's own 8 t+1 loads retired; barrier
// publishes). vmcnt never drains to 0 mid-loop (t+2's 8 stay in flight).
// K-loop unrolled x2 with ping-ponged frag names (all compile-time indices).
// LDS 128KB, 128B rows, verified zero-conflict XOR swizzle (granule g of row
// r holds global granule g^(r&7); read pg=((kk>>3)+gsel)^(mrow&7)).
__global__ __launch_bounds__(512, 2) void gemm_bt_bias(
    const unsigned short* __restrict__ A,   // [M][K] bf16 bits
    const unsigned short* __restrict__ B,   // [N][K] bf16 bits
    const float* __restrict__ bmu, const float* __restrict__ blv,
    const float* __restrict__ beps,
    float* __restrict__ C, int M, int N, int K) {
  __shared__ __align__(16) unsigned short As[2][2][128 * 64];  // 64 KB
  __shared__ __align__(16) unsigned short Bs[2][2][128 * 64];  // 64 KB

  const int tid  = threadIdx.x;
  const int wave = tid >> 6;
  const int lane = tid & 63;
  const int wm = wave >> 2;   // 0..1  (M half)
  const int wn = wave & 3;    // 0..3  (N quarter)

  const int rowA0 = blockIdx.y * 256;
  const int rowB0 = blockIdx.x * 256;

  const int srow = tid >> 3;                       // 0..63
  const int scol = ((tid & 7) ^ (srow & 7)) * 8;
  const unsigned short* pA = A + (size_t)(rowA0 + srow) * K + scol;
  const unsigned short* pB = B + (size_t)(rowB0 + srow) * K + scol;
  const int dep = wave * 512;   // wave-uniform deposit base (elems) per round

#define GLL(srcp, dstp)                                                     \
  __builtin_amdgcn_global_load_lds(                                         \
      (const __attribute__((address_space(1))) unsigned int*)(srcp),        \
      (__attribute__((address_space(3))) unsigned int*)(dstp), 16, 0, 0)

#define STAGE_A(kt, b, h) do {                                              \
    const unsigned short* s_ = pA + (size_t)((h) * 128) * K + (size_t)(kt) * 64; \
    GLL(s_, &As[b][h][dep]);                                                \
    GLL(s_ + (size_t)64 * K, &As[b][h][4096 + dep]); } while (0)
#define STAGE_B(kt, b, h) do {                                              \
    const unsigned short* s_ = pB + (size_t)((h) * 128) * K + (size_t)(kt) * 64; \
    GLL(s_, &Bs[b][h][dep]);                                                \
    GLL(s_ + (size_t)64 * K, &Bs[b][h][4096 + dep]); } while (0)

  f32x4 acc[8][4];
#pragma unroll
  for (int i = 0; i < 8; ++i)
#pragma unroll
    for (int j = 0; j < 4; ++j)
      acc[i][j] = (f32x4){0.f, 0.f, 0.f, 0.f};

  const int mrow = lane & 15;   // fragment row
  const int gsel = lane >> 4;   // k-granule select 0..3
  const int pgL = (gsel ^ (mrow & 7)) * 8;         // kk=0
  const int pgH = ((4 + gsel) ^ (mrow & 7)) * 8;   // kk=32
  const int aoff = mrow * 64;
  const int boff = ((wn & 1) * 64 + mrow) * 64;

#define BAR() do { __builtin_amdgcn_s_barrier();                            \
                   __builtin_amdgcn_sched_barrier(0); } while (0)
#define DRAIN_LGKM() do { asm volatile("s_waitcnt lgkmcnt(0)" ::: "memory");\
                          __builtin_amdgcn_sched_barrier(0); } while (0)

  // prologue: stage tiles 0,1; certify tile 0; pre-read tile 0's P0 frags.
  STAGE_A(0, 0, 0); STAGE_A(0, 0, 1); STAGE_B(0, 0, 0); STAGE_B(0, 0, 1);
  STAGE_A(1, 1, 0); STAGE_A(1, 1, 1); STAGE_B(1, 1, 0); STAGE_B(1, 1, 1);
  asm volatile("s_waitcnt vmcnt(8)" ::: "memory");
  BAR();

  bf16x8 aX[4][2], bX01[2][2], aY[4][2], bY01[2][2];  // ping-pong P0 frags
  bf16x8 a1[4][2], b23[2][2];                         // intra-tile temps
  {
    const unsigned short* as0 = &As[0][wm][0];
    const unsigned short* bs0 = &Bs[0][wn >> 1][0];
#pragma unroll
    for (int mi = 0; mi < 4; ++mi) {
      aX[mi][0] = *(const bf16x8*)&as0[aoff + mi * 1024 + pgL];
      aX[mi][1] = *(const bf16x8*)&as0[aoff + mi * 1024 + pgH];
    }
#pragma unroll
    for (int ni = 0; ni < 2; ++ni) {
      bX01[ni][0] = *(const bf16x8*)&bs0[boff + ni * 1024 + pgL];
      bX01[ni][1] = *(const bf16x8*)&bs0[boff + ni * 1024 + pgH];
    }
    DRAIN_LGKM();
  }

  const int NT = K / 64;   // 64 (even)

#define TILE(T, CB, NB, A0, B01, A0N, B01N) do {                              \
    const unsigned short* as_  = &As[CB][wm][0];                              \
    const unsigned short* bs_  = &Bs[CB][wn >> 1][0];                         \
    const unsigned short* asn_ = &As[NB][wm][0];                              \
    const unsigned short* bsn_ = &Bs[NB][wn >> 1][0];                         \
    const bool pf = ((T) + 2 < NT);                                           \
    const bool pr = ((T) + 1 < NT);                                           \
    /* P0: MFMA A0 x B01 ; read a1 */                                         \
    _Pragma("unroll")                                                         \
    for (int mi = 0; mi < 4; ++mi) {                                          \
      a1[mi][0] = *(const bf16x8*)&as_[aoff + (mi + 4) * 1024 + pgL];         \
      a1[mi][1] = *(const bf16x8*)&as_[aoff + (mi + 4) * 1024 + pgH];         \
    }                                                                         \
    __builtin_amdgcn_s_setprio(1);                                            \
    _Pragma("unroll")                                                         \
    for (int kk = 0; kk < 2; ++kk)                                            \
      _Pragma("unroll")                                                       \
      for (int mi = 0; mi < 4; ++mi)                                          \
        _Pragma("unroll")                                                     \
        for (int ni = 0; ni < 2; ++ni)                                        \
          acc[mi][ni] = __builtin_amdgcn_mfma_f32_16x16x32_bf16(              \
              A0[mi][kk], B01[ni][kk], acc[mi][ni], 0, 0, 0);                 \
    __builtin_amdgcn_s_setprio(0);                                            \
    DRAIN_LGKM(); BAR();                                                      \
    /* P1: MFMA a1 x B01 ; read b23 ; stage A(T+2) */                         \
    _Pragma("unroll")                                                         \
    for (int ni = 0; ni < 2; ++ni) {                                          \
      b23[ni][0] = *(const bf16x8*)&bs_[boff + (ni + 2) * 1024 + pgL];        \
      b23[ni][1] = *(const bf16x8*)&bs_[boff + (ni + 2) * 1024 + pgH];        \
    }                                                                         \
    if (pf) { STAGE_A((T) + 2, CB, 0); STAGE_A((T) + 2, CB, 1); }             \
    __builtin_amdgcn_s_setprio(1);                                            \
    _Pragma("unroll")                                                         \
    for (int kk = 0; kk < 2; ++kk)                                            \
      _Pragma("unroll")                                                       \
      for (int mi = 0; mi < 4; ++mi)                                          \
        _Pragma("unroll")                                                     \
        for (int ni = 0; ni < 2; ++ni)                                        \
          acc[mi + 4][ni] = __builtin_amdgcn_mfma_f32_16x16x32_bf16(          \
              a1[mi][kk], B01[ni][kk], acc[mi + 4][ni], 0, 0, 0);             \
    __builtin_amdgcn_s_setprio(0);                                            \
    DRAIN_LGKM(); BAR();                                                      \
    /* P2: MFMA a1 x b23 ; stage B(T+2) ; counted boundary vmcnt */           \
    if (pf) { STAGE_B((T) + 2, CB, 0); STAGE_B((T) + 2, CB, 1); }             \
    __builtin_amdgcn_s_setprio(1);                                            \
    _Pragma("unroll")                                                         \
    for (int kk = 0; kk < 2; ++kk)                                            \
      _Pragma("unroll")                                                       \
      for (int mi = 0; mi < 4; ++mi)                                          \
        _Pragma("unroll")                                                     \
        for (int ni = 0; ni < 2; ++ni)                                        \
          acc[mi + 4][ni + 2] = __builtin_amdgcn_mfma_f32_16x16x32_bf16(      \
              a1[mi][kk], b23[ni][kk], acc[mi + 4][ni + 2], 0, 0, 0);         \
    __builtin_amdgcn_s_setprio(0);                                            \
    if (pr) {                                                                 \
      if (pf) { asm volatile("s_waitcnt vmcnt(8)" ::: "memory"); }            \
      else    { asm volatile("s_waitcnt vmcnt(0)" ::: "memory"); }            \
      __builtin_amdgcn_sched_barrier(0);                                      \
    }                                                                         \
    BAR();                                                                    \
    /* P3: MFMA A0 x b23 ; pre-read next tile's A0N,B01N from buf NB */       \
    if (pr) {                                                                 \
      _Pragma("unroll")                                                       \
      for (int mi = 0; mi < 4; ++mi) {                                        \
        A0N[mi][0] = *(const bf16x8*)&asn_[aoff + mi * 1024 + pgL];           \
        A0N[mi][1] = *(const bf16x8*)&asn_[aoff + mi * 1024 + pgH];           \
      }                                                                       \
      _Pragma("unroll")                                                       \
      for (int ni = 0; ni < 2; ++ni) {                                        \
        B01N[ni][0] = *(const bf16x8*)&bsn_[boff + ni * 1024 + pgL];          \
        B01N[ni][1] = *(const bf16x8*)&bsn_[boff + ni * 1024 + pgH];          \
      }                                                                       \
    }                                                                         \
    __builtin_amdgcn_s_setprio(1);                                            \
    _Pragma("unroll")                                                         \
    for (int kk = 0; kk < 2; ++kk)                                            \
      _Pragma("unroll")                                                       \
      for (int mi = 0; mi < 4; ++mi)                                          \
        _Pragma("unroll")                                                     \
        for (int ni = 0; ni < 2; ++ni)                                        \
          acc[mi][ni + 2] = __builtin_amdgcn_mfma_f32_16x16x32_bf16(          \
              A0[mi][kk], b23[ni][kk], acc[mi][ni + 2], 0, 0, 0);             \
    __builtin_amdgcn_s_setprio(0);                                            \
    DRAIN_LGKM(); BAR();                                                      \
  } while (0)

  for (int t = 0; t < NT; t += 2) {
    TILE(t,     0, 1, aX, bX01, aY, bY01);
    TILE(t + 1, 1, 0, aY, bY01, aX, bX01);
  }

  // Epilogue: C/D layout col=lane&15, row=(lane>>4)*4+reg (m89-verified).
  const int colq = lane & 15;
  const int rq4  = (lane >> 4) * 4;
#pragma unroll
  for (int ni = 0; ni < 4; ++ni) {
    const int col = rowB0 + wn * 64 + ni * 16 + colq;
    const float bias = bmu[col] + beps[col] * __expf(0.5f * blv[col]);
#pragma unroll
    for (int mi = 0; mi < 8; ++mi) {
      const int rbase = rowA0 + wm * 128 + mi * 16 + rq4;
#pragma unroll
      for (int r = 0; r < 4; ++r)
        C[(size_t)(rbase + r) * N + col] = acc[mi][ni][r] + bias;
    }
  }
#undef GLL
#undef STAGE_A
#undef STAGE_B
#undef BAR
#undef DRAIN_LGKM
#undef TILE
}

extern "C" void kernel_launch(void* const* d_in, const int* in_sizes, int n_in,
                              void* d_out, int out_size, void* d_ws, size_t ws_size,
                              hipStream_t stream) {
  const float* x    = (const float*)d_in[0];
  const float* wmu  = (const float*)d_in[1];
  const float* wlv  = (const float*)d_in[2];
  const float* bmu  = (const float*)d_in[3];
  const float* blv  = (const float*)d_in[4];
  const float* weps = (const float*)d_in[5];
  const float* beps = (const float*)d_in[6];
  float* out = (float*)d_out;

  const int M = 8192, N = 4096, K = 4096;

  // workspace: xbf [M*K] bf16 (64 MB) then wbf [N*K] bf16 (32 MB)
  unsigned short* xbf = (unsigned short*)d_ws;
  unsigned short* wbf = xbf + (size_t)M * K;

  const int n8w = N * K / 8;
  prep_weight<<<n8w / 256, 256, 0, stream>>>(
      (const float4*)wmu, (const float4*)wlv, (const float4*)weps,
      (u16x8*)wbf, n8w);
  const int n8x = M * K / 8;
  prep_x<<<n8x / 256, 256, 0, stream>>>((const float4*)x, (u16x8*)xbf, n8x);

  dim3 grid(N / 256, M / 256);  // 16 x 32 = 512 blocks
  gemm_bt_bias<<<grid, 512, 0, stream>>>(xbf, wbf, bmu, blv, beps, out, M, N, K);
}

// Round 7
// 603.601 us; speedup vs baseline: 2.9644x; 2.9644x over previous
//
#include <hip/hip_runtime.h>
#include <hip/hip_bf16.h>
#include <stdint.h>

typedef __bf16 bf16x8 __attribute__((ext_vector_type(8)));
typedef float f32x4 __attribute__((ext_vector_type(4)));
typedef unsigned short u16x8 __attribute__((ext_vector_type(8)));

// float -> bf16 round-to-nearest-even (bit trick; inputs are finite here)
__device__ inline unsigned short f2bf_rne(float f) {
  unsigned int u = __float_as_uint(f);
  u += 0x7fffu + ((u >> 16) & 1u);
  return (unsigned short)(u >> 16);
}

// w = mu + eps * exp(0.5*lv), packed bf16. 8 elems/thread, 16B store.
__global__ __launch_bounds__(256) void prep_weight(
    const float4* __restrict__ mu, const float4* __restrict__ lv,
    const float4* __restrict__ eps, u16x8* __restrict__ wbf, int n8) {
  int i = blockIdx.x * 256 + threadIdx.x;
  if (i >= n8) return;
  float4 m0 = mu[2 * i], m1 = mu[2 * i + 1];
  float4 v0 = lv[2 * i], v1 = lv[2 * i + 1];
  float4 e0 = eps[2 * i], e1 = eps[2 * i + 1];
  u16x8 p;
  p[0] = f2bf_rne(m0.x + e0.x * __expf(0.5f * v0.x));
  p[1] = f2bf_rne(m0.y + e0.y * __expf(0.5f * v0.y));
  p[2] = f2bf_rne(m0.z + e0.z * __expf(0.5f * v0.z));
  p[3] = f2bf_rne(m0.w + e0.w * __expf(0.5f * v0.w));
  p[4] = f2bf_rne(m1.x + e1.x * __expf(0.5f * v1.x));
  p[5] = f2bf_rne(m1.y + e1.y * __expf(0.5f * v1.y));
  p[6] = f2bf_rne(m1.z + e1.z * __expf(0.5f * v1.z));
  p[7] = f2bf_rne(m1.w + e1.w * __expf(0.5f * v1.w));
  wbf[i] = p;
}

__global__ __launch_bounds__(256) void prep_x(
    const float4* __restrict__ x, u16x8* __restrict__ xbf, int n8) {
  int i = blockIdx.x * 256 + threadIdx.x;
  if (i >= n8) return;
  float4 m0 = x[2 * i], m1 = x[2 * i + 1];
  u16x8 p;
  p[0] = f2bf_rne(m0.x); p[1] = f2bf_rne(m0.y);
  p[2] = f2bf_rne(m0.z); p[3] = f2bf_rne(m0.w);
  p[4] = f2bf_rne(m1.x); p[5] = f2bf_rne(m1.y);
  p[6] = f2bf_rne(m1.z); p[7] = f2bf_rne(m1.w);
  xbf[i] = p;
}

// C[M,N] = A[M,K]*B[N,K]^T + bias(N). 256x256 tile, BK=64, 512 thr = 8 waves
// (2M x 4N), per-wave 128x64: acc[8][4] (128 AGPR), 64 MFMA/K-tile in 4
// register-resident quadrants Q0..Q3.
// R7: TWO barriers per K-tile (R5 had 8 + 4 full lgkm drains -> ~3300cy/tile
// sync overhead vs 2483cy MFMA floor). The in-place staging needs only:
//   SYNC1 (lgkmcnt(0)+barrier): all waves' buf[c] ds_reads RETIRED -> stages
//         for tile t+2 may overwrite buf[c].
//   SYNC2 (vmcnt(8)+barrier): tile t+1's 8 loads certified (in-order vmcnt
//         retires the 8 oldest; t+2's 8 stay IN FLIGHT - never drains to 0
//         mid-loop) -> buf[n] readable next iteration.
// Between syncs waves free-run: Q2/Q3 are register-only so they execute after
// SYNC1, overlapping the 8 stage issues + DMA; compiler inserts fine-grained
// lgkm waits for read->MFMA deps (near-optimal per m97 asm evidence); waves
// drift -> cross-wave MFMA/LDS overlap; setprio(1) arbitrates for MFMA.
// Register budget note (R6 lesson): 2 waves/SIMD cap = 256 regs/wave total;
// acc 128 AGPR + 96 frag VGPR + addressing = saturated. NO extra pipeline
// state is affordable; this schedule adds none.
// LDS 128KB, 128B rows, verified zero-conflict XOR swizzle (granule g of row
// r holds global granule g^(r&7); read pg=((kk>>3)+gsel)^(mrow&7)).
__global__ __launch_bounds__(512, 2) void gemm_bt_bias(
    const unsigned short* __restrict__ A,   // [M][K] bf16 bits
    const unsigned short* __restrict__ B,   // [N][K] bf16 bits
    const float* __restrict__ bmu, const float* __restrict__ blv,
    const float* __restrict__ beps,
    float* __restrict__ C, int M, int N, int K) {
  __shared__ __align__(16) unsigned short As[2][2][128 * 64];  // 64 KB
  __shared__ __align__(16) unsigned short Bs[2][2][128 * 64];  // 64 KB

  const int tid  = threadIdx.x;
  const int wave = tid >> 6;
  const int lane = tid & 63;
  const int wm = wave >> 2;   // 0..1  (M half)
  const int wn = wave & 3;    // 0..3  (N quarter)

  const int rowA0 = blockIdx.y * 256;
  const int rowB0 = blockIdx.x * 256;

  const int srow = tid >> 3;                       // 0..63
  const int scol = ((tid & 7) ^ (srow & 7)) * 8;
  const unsigned short* pA = A + (size_t)(rowA0 + srow) * K + scol;
  const unsigned short* pB = B + (size_t)(rowB0 + srow) * K + scol;
  const int dep = wave * 512;   // wave-uniform deposit base (elems) per round

#define GLL(srcp, dstp)                                                     \
  __builtin_amdgcn_global_load_lds(                                         \
      (const __attribute__((address_space(1))) unsigned int*)(srcp),        \
      (__attribute__((address_space(3))) unsigned int*)(dstp), 16, 0, 0)

#define STAGE_A(kt, b, h) do {                                              \
    const unsigned short* s_ = pA + (size_t)((h) * 128) * K + (size_t)(kt) * 64; \
    GLL(s_, &As[b][h][dep]);                                                \
    GLL(s_ + (size_t)64 * K, &As[b][h][4096 + dep]); } while (0)
#define STAGE_B(kt, b, h) do {                                              \
    const unsigned short* s_ = pB + (size_t)((h) * 128) * K + (size_t)(kt) * 64; \
    GLL(s_, &Bs[b][h][dep]);                                                \
    GLL(s_ + (size_t)64 * K, &Bs[b][h][4096 + dep]); } while (0)

  f32x4 acc[8][4];
#pragma unroll
  for (int i = 0; i < 8; ++i)
#pragma unroll
    for (int j = 0; j < 4; ++j)
      acc[i][j] = (f32x4){0.f, 0.f, 0.f, 0.f};

  const int mrow = lane & 15;   // fragment row
  const int gsel = lane >> 4;   // k-granule select 0..3
  const int pgL = (gsel ^ (mrow & 7)) * 8;         // kk=0
  const int pgH = ((4 + gsel) ^ (mrow & 7)) * 8;   // kk=32
  const int aoff = mrow * 64;
  const int boff = ((wn & 1) * 64 + mrow) * 64;

  // prologue: stage tiles 0,1; certify tile 0 (tile 1's 8 stay in flight).
  STAGE_A(0, 0, 0); STAGE_A(0, 0, 1); STAGE_B(0, 0, 0); STAGE_B(0, 0, 1);
  STAGE_A(1, 1, 0); STAGE_A(1, 1, 1); STAGE_B(1, 1, 0); STAGE_B(1, 1, 1);
  asm volatile("s_waitcnt vmcnt(8)" ::: "memory");
  __builtin_amdgcn_s_barrier();
  __builtin_amdgcn_sched_barrier(0);

  bf16x8 a0[4][2], a1[4][2], b01[2][2], b23[2][2];

  const int NT = K / 64;   // 64
  for (int t = 0; t < NT; ++t) {
    const int c = t & 1;
    const unsigned short* as_ = &As[c][wm][0];
    const unsigned short* bs_ = &Bs[c][wn >> 1][0];
    const bool pf = (t + 2 < NT);
    const bool pr = (t + 1 < NT);

    // reads for Q0 (a0, b01) and Q1 (a1) — issue together; the compiler's
    // dependence-tracked lgkm waits let Q0 start as soon as its 12 arrive.
#pragma unroll
    for (int mi = 0; mi < 4; ++mi) {
      a0[mi][0] = *(const bf16x8*)&as_[aoff + mi * 1024 + pgL];
      a0[mi][1] = *(const bf16x8*)&as_[aoff + mi * 1024 + pgH];
    }
#pragma unroll
    for (int ni = 0; ni < 2; ++ni) {
      b01[ni][0] = *(const bf16x8*)&bs_[boff + ni * 1024 + pgL];
      b01[ni][1] = *(const bf16x8*)&bs_[boff + ni * 1024 + pgH];
    }
#pragma unroll
    for (int mi = 0; mi < 4; ++mi) {
      a1[mi][0] = *(const bf16x8*)&as_[aoff + (mi + 4) * 1024 + pgL];
      a1[mi][1] = *(const bf16x8*)&as_[aoff + (mi + 4) * 1024 + pgH];
    }

    // Q0: a0 x b01 -> acc[0..3][0..1]
    __builtin_amdgcn_s_setprio(1);
#pragma unroll
    for (int kk = 0; kk < 2; ++kk)
#pragma unroll
      for (int mi = 0; mi < 4; ++mi)
#pragma unroll
        for (int ni = 0; ni < 2; ++ni)
          acc[mi][ni] = __builtin_amdgcn_mfma_f32_16x16x32_bf16(
              a0[mi][kk], b01[ni][kk], acc[mi][ni], 0, 0, 0);
    __builtin_amdgcn_s_setprio(0);

    // reads for Q2/Q3 (b23) — last LDS reads of buf[c]
#pragma unroll
    for (int ni = 0; ni < 2; ++ni) {
      b23[ni][0] = *(const bf16x8*)&bs_[boff + (ni + 2) * 1024 + pgL];
      b23[ni][1] = *(const bf16x8*)&bs_[boff + (ni + 2) * 1024 + pgH];
    }

    // Q1: a1 x b01 -> acc[4..7][0..1]
    __builtin_amdgcn_s_setprio(1);
#pragma unroll
    for (int kk = 0; kk < 2; ++kk)
#pragma unroll
      for (int mi = 0; mi < 4; ++mi)
#pragma unroll
        for (int ni = 0; ni < 2; ++ni)
          acc[mi + 4][ni] = __builtin_amdgcn_mfma_f32_16x16x32_bf16(
              a1[mi][kk], b01[ni][kk], acc[mi + 4][ni], 0, 0, 0);
    __builtin_amdgcn_s_setprio(0);

    // SYNC1: every wave's buf[c] reads retired -> stages may overwrite buf[c]
    asm volatile("s_waitcnt lgkmcnt(0)" ::: "memory");
    __builtin_amdgcn_sched_barrier(0);
    __builtin_amdgcn_s_barrier();
    __builtin_amdgcn_sched_barrier(0);

    if (pf) {
      STAGE_A(t + 2, c, 0); STAGE_A(t + 2, c, 1);
      STAGE_B(t + 2, c, 0); STAGE_B(t + 2, c, 1);
    }

    // Q2: a1 x b23 -> acc[4..7][2..3]  (register-only; overlaps stage DMA)
    __builtin_amdgcn_s_setprio(1);
#pragma unroll
    for (int kk = 0; kk < 2; ++kk)
#pragma unroll
      for (int mi = 0; mi < 4; ++mi)
#pragma unroll
        for (int ni = 0; ni < 2; ++ni)
          acc[mi + 4][ni + 2] = __builtin_amdgcn_mfma_f32_16x16x32_bf16(
              a1[mi][kk], b23[ni][kk], acc[mi + 4][ni + 2], 0, 0, 0);
    __builtin_amdgcn_s_setprio(0);

    // Q3: a0 x b23 -> acc[0..3][2..3]
    __builtin_amdgcn_s_setprio(1);
#pragma unroll
    for (int kk = 0; kk < 2; ++kk)
#pragma unroll
      for (int mi = 0; mi < 4; ++mi)
#pragma unroll
        for (int ni = 0; ni < 2; ++ni)
          acc[mi][ni + 2] = __builtin_amdgcn_mfma_f32_16x16x32_bf16(
              a0[mi][kk], b23[ni][kk], acc[mi][ni + 2], 0, 0, 0);
    __builtin_amdgcn_s_setprio(0);

    // SYNC2: certify tile t+1 (counted; t+2's 8 loads remain in flight)
    if (pr) {
      if (pf) { asm volatile("s_waitcnt vmcnt(8)" ::: "memory"); }
      else    { asm volatile("s_waitcnt vmcnt(0)" ::: "memory"); }
      __builtin_amdgcn_sched_barrier(0);
      __builtin_amdgcn_s_barrier();
      __builtin_amdgcn_sched_barrier(0);
    }
  }

  // Epilogue: C/D layout col=lane&15, row=(lane>>4)*4+reg (m89-verified).
  const int colq = lane & 15;
  const int rq4  = (lane >> 4) * 4;
#pragma unroll
  for (int ni = 0; ni < 4; ++ni) {
    const int col = rowB0 + wn * 64 + ni * 16 + colq;
    const float bias = bmu[col] + beps[col] * __expf(0.5f * blv[col]);
#pragma unroll
    for (int mi = 0; mi < 8; ++mi) {
      const int rbase = rowA0 + wm * 128 + mi * 16 + rq4;
#pragma unroll
      for (int r = 0; r < 4; ++r)
        C[(size_t)(rbase + r) * N + col] = acc[mi][ni][r] + bias;
    }
  }
#undef GLL
#undef STAGE_A
#undef STAGE_B
}

extern "C" void kernel_launch(void* const* d_in, const int* in_sizes, int n_in,
                              void* d_out, int out_size, void* d_ws, size_t ws_size,
                              hipStream_t stream) {
  const float* x    = (const float*)d_in[0];
  const float* wmu  = (const float*)d_in[1];
  const float* wlv  = (const float*)d_in[2];
  const float* bmu  = (const float*)d_in[3];
  const float* blv  = (const float*)d_in[4];
  const float* weps = (const float*)d_in[5];
  const float* beps = (const float*)d_in[6];
  float* out = (float*)d_out;

  const int M = 8192, N = 4096, K = 4096;

  // workspace: xbf [M*K] bf16 (64 MB) then wbf [N*K] bf16 (32 MB)
  unsigned short* xbf = (unsigned short*)d_ws;
  unsigned short* wbf = xbf + (size_t)M * K;

  const int n8w = N * K / 8;
  prep_weight<<<n8w / 256, 256, 0, stream>>>(
      (const float4*)wmu, (const float4*)wlv, (const float4*)weps,
      (u16x8*)wbf, n8w);
  const int n8x = M * K / 8;
  prep_x<<<n8x / 256, 256, 0, stream>>>((const float4*)x, (u16x8*)xbf, n8x);

  dim3 grid(N / 256, M / 256);  // 16 x 32 = 512 blocks
  gemm_bt_bias<<<grid, 512, 0, stream>>>(xbf, wbf, bmu, blv, beps, out, M, N, K);
}